// Round 1
// baseline (2124.498 us; speedup 1.0000x reference)
//
#include <hip/hip_runtime.h>
#include <math.h>

// SpatialAttention: B=8, C_IN=256, C_OUT=128, N=64*64=4096
//   Q[b,n,o]  = sum_c p[b,c,n]*Wq[o,c] + bq[o]           (n-major in ws)
//   Kt[b,n,o] = sum_c b[b,c,n]*Wk[o,c] + bk[o]           (n-major in ws)
//   S[n,m]    = sum_o Q[n,o]*Kt[m,o];  P = softmax_m(S)
//   out[b,c,n]= sum_m P[n,m]*b[b,c,m]  -> uses Vt[b,m,c] = b[b,c,m]
//
// Strategy: flash-style online softmax, 64-row Q tiles, 32-key tiles.
// fp32 everywhere (round 0: correctness baseline; fp32 VALU floor ~660us).

#define B_   8
#define CIN  256
#define COUT 128
#define NN   4096

// out[b][n][o] = sum_c in[b][c][n] * W[o][c] + bias[o]
__global__ __launch_bounds__(256) void proj_kernel(const float* __restrict__ in,
                                                   const float* __restrict__ W,
                                                   const float* __restrict__ bias,
                                                   float* __restrict__ out) {
    const int bx = blockIdx.x;           // 512 blocks: b*64 + ntile
    const int b  = bx >> 6;
    const int n0 = (bx & 63) << 6;       // 64-n tile
    const int t  = threadIdx.x;
    const int o  = t & 127;
    const int half = t >> 7;             // 0/1 -> 32 n each
    const int nbase = n0 + half * 32;

    float acc[32];
    const float bo = bias[o];
#pragma unroll
    for (int i = 0; i < 32; ++i) acc[i] = bo;

    const float* wrow = W + o * CIN;
    const float* inb  = in + (size_t)b * CIN * NN + nbase;
    for (int c = 0; c < CIN; c += 4) {
        const float4 w4 = *(const float4*)(wrow + c);
        const float wv[4] = {w4.x, w4.y, w4.z, w4.w};
#pragma unroll
        for (int cc = 0; cc < 4; ++cc) {
            const float* src = inb + (size_t)(c + cc) * NN;
            const float wvc = wv[cc];
#pragma unroll
            for (int k = 0; k < 8; ++k) {
                float4 v = *(const float4*)(src + k * 4);  // wave-uniform (broadcast)
                acc[k*4+0] += wvc * v.x;
                acc[k*4+1] += wvc * v.y;
                acc[k*4+2] += wvc * v.z;
                acc[k*4+3] += wvc * v.w;
            }
        }
    }
    float* outp = out + ((size_t)b * NN + nbase) * COUT + o;   // lanes: consecutive o -> coalesced
#pragma unroll
    for (int i = 0; i < 32; ++i) outp[(size_t)i * COUT] = acc[i];
}

// in [B][256][4096] -> outT [B][4096][256]
__global__ __launch_bounds__(256) void transpose_kernel(const float* __restrict__ in,
                                                        float* __restrict__ outT) {
    __shared__ float T[64][65];
    const int bx = blockIdx.x;            // 8 * 64 * 4 = 2048 blocks
    const int b  = bx >> 8;
    const int m0 = ((bx >> 2) & 63) << 6;
    const int c0 = (bx & 3) << 6;
    const int t  = threadIdx.x;
#pragma unroll
    for (int k = 0; k < 16; ++k) {
        int id = t + k * 256;
        int i = id >> 6, j = id & 63;     // i: c-local, j: m-local (lanes: consec j -> coalesced)
        T[i][j] = in[((size_t)b * CIN + c0 + i) * NN + m0 + j];
    }
    __syncthreads();
#pragma unroll
    for (int k = 0; k < 16; ++k) {
        int id = t + k * 256;
        int ml = id >> 6, cl = id & 63;   // lanes: consec cl -> coalesced write
        outT[((size_t)b * NN + m0 + ml) * CIN + c0 + cl] = T[cl][ml];
    }
}

// Q [B][N][128], Kt [B][N][128], Vt [B][N][256], out [B][256][N]
__global__ __launch_bounds__(256, 2) void flash_kernel(const float* __restrict__ Q,
                                                       const float* __restrict__ Kt,
                                                       const float* __restrict__ Vt,
                                                       float* __restrict__ out) {
    // Swizzled tiles: element (row r, col o) stored at chunk (o>>2) ^ ((r>>2)&7).
    __shared__ float Qs[64 * 128];     // 32 KB
    __shared__ float Ks[32 * 128];     // 16 KB
    __shared__ float Pt[32 * 68];      // P transposed [m][n], pad 68 -> 8.7 KB
    __shared__ float alphas[64];
    __shared__ float ls[64];

    const int bx   = blockIdx.x;       // 512 = B * 64 q-tiles
    const int b    = bx >> 6;
    const int q0   = (bx & 63) << 6;
    const int t    = threadIdx.x;
    const int w    = t >> 6;           // wave 0..3
    const int lane = t & 63;

    // ---- load Q tile (swizzled) ----
    {
        const float* Qg = Q + ((size_t)b * NN + q0) * COUT;
#pragma unroll
        for (int it = 0; it < 8; ++it) {
            int id = t + it * 256;                 // 64 rows * 32 chunks
            int r = id >> 5, co = id & 31;
            float4 v = *(const float4*)(Qg + r * COUT + co * 4);
            int c2 = co ^ ((r >> 2) & 7);
            *(float4*)(&Qs[r * 128 + c2 * 4]) = v;
        }
    }

    // S-phase map: lane -> (m-group, row-pair)
    const int tmS = lane & 7;          // m = 4*tmS + j
    const int lnS = lane >> 3;         // n = w*16 + 2*lnS + i
    const int nS0 = w * 16 + 2 * lnS;
    // PV map: wave w owns rows w*16..+15; lane owns c = lane*4..+3
    const int c0  = lane * 4;
    const int nP0 = w * 16;

    float m_run[2] = {-1e30f, -1e30f};
    float l_run[2] = {0.f, 0.f};
    float O[16][4];
#pragma unroll
    for (int a = 0; a < 16; ++a)
#pragma unroll
        for (int c = 0; c < 4; ++c) O[a][c] = 0.f;

    for (int k0 = 0; k0 < NN; k0 += 32) {
        __syncthreads();   // protect Ks/Pt from previous iteration's readers
        // ---- load K tile (swizzled) ----
        {
            const float* Kg = Kt + ((size_t)b * NN + k0) * COUT;
#pragma unroll
            for (int it = 0; it < 4; ++it) {
                int id = t + it * 256;             // 32 rows * 32 chunks
                int r = id >> 5, co = id & 31;
                float4 v = *(const float4*)(Kg + r * COUT + co * 4);
                int c2 = co ^ ((r >> 2) & 7);
                *(float4*)(&Ks[r * 128 + c2 * 4]) = v;
            }
        }
        __syncthreads();

        // ---- S = Q K^T for this tile: s[i][j], i in 2 rows, j in 4 m ----
        float s[2][4] = {{0.f,0.f,0.f,0.f},{0.f,0.f,0.f,0.f}};
        const int qk0 = ((nS0    ) >> 2) & 7;
        const int qk1 = ((nS0 + 1) >> 2) & 7;
#pragma unroll 4
        for (int o = 0; o < 128; o += 4) {
            const int co = o >> 2;
            float4 qa0 = *(const float4*)(&Qs[(nS0    ) * 128 + ((co ^ qk0) << 2)]);
            float4 qa1 = *(const float4*)(&Qs[(nS0 + 1) * 128 + ((co ^ qk1) << 2)]);
            float4 kb[4];
#pragma unroll
            for (int j = 0; j < 4; ++j)
                kb[j] = *(const float4*)(&Ks[(4 * tmS + j) * 128 + ((co ^ tmS) << 2)]);
#pragma unroll
            for (int j = 0; j < 4; ++j) {
                s[0][j] += qa0.x*kb[j].x + qa0.y*kb[j].y + qa0.z*kb[j].z + qa0.w*kb[j].w;
                s[1][j] += qa1.x*kb[j].x + qa1.y*kb[j].y + qa1.z*kb[j].z + qa1.w*kb[j].w;
            }
        }

        // ---- online softmax (row reduction across the 8 tm lanes) ----
        float alpha[2];
#pragma unroll
        for (int i = 0; i < 2; ++i) {
            float mx = fmaxf(fmaxf(s[i][0], s[i][1]), fmaxf(s[i][2], s[i][3]));
            mx = fmaxf(mx, __shfl_xor(mx, 1));
            mx = fmaxf(mx, __shfl_xor(mx, 2));
            mx = fmaxf(mx, __shfl_xor(mx, 4));
            const float mn = fmaxf(m_run[i], mx);
            alpha[i] = __expf(m_run[i] - mn);
            m_run[i] = mn;
            float ssum = 0.f;
#pragma unroll
            for (int j = 0; j < 4; ++j) { s[i][j] = __expf(s[i][j] - mn); ssum += s[i][j]; }
            ssum += __shfl_xor(ssum, 1);
            ssum += __shfl_xor(ssum, 2);
            ssum += __shfl_xor(ssum, 4);
            l_run[i] = l_run[i] * alpha[i] + ssum;
        }
        // write P^T and per-row alpha / running-l
#pragma unroll
        for (int i = 0; i < 2; ++i) {
            const int n = nS0 + i;
#pragma unroll
            for (int j = 0; j < 4; ++j) Pt[(4 * tmS + j) * 68 + n] = s[i][j];
            if (tmS == 0) { alphas[n] = alpha[i]; ls[n] = l_run[i]; }
        }
        __syncthreads();

        // ---- PV: O[nn][cc] = O*alpha + sum_m P^T[m][n] * Vt[m][c] ----
#pragma unroll
        for (int nn = 0; nn < 16; ++nn) {
            const float a = alphas[nP0 + nn];
            O[nn][0] *= a; O[nn][1] *= a; O[nn][2] *= a; O[nn][3] *= a;
        }
        const float* Vg = Vt + ((size_t)b * NN + k0) * CIN + c0;
#pragma unroll 4
        for (int mm = 0; mm < 32; ++mm) {
            const float4 v = *(const float4*)(Vg + (size_t)mm * CIN);   // 1KB/wave coalesced
            const float* prow = &Pt[mm * 68 + nP0];                      // wave-uniform (broadcast)
#pragma unroll
            for (int q = 0; q < 4; ++q) {
                const float4 p4 = *(const float4*)(prow + q * 4);
                O[q*4+0][0] += p4.x*v.x; O[q*4+0][1] += p4.x*v.y; O[q*4+0][2] += p4.x*v.z; O[q*4+0][3] += p4.x*v.w;
                O[q*4+1][0] += p4.y*v.x; O[q*4+1][1] += p4.y*v.y; O[q*4+1][2] += p4.y*v.z; O[q*4+1][3] += p4.y*v.w;
                O[q*4+2][0] += p4.z*v.x; O[q*4+2][1] += p4.z*v.y; O[q*4+2][2] += p4.z*v.z; O[q*4+2][3] += p4.z*v.w;
                O[q*4+3][0] += p4.w*v.x; O[q*4+3][1] += p4.w*v.y; O[q*4+3][2] += p4.w*v.z; O[q*4+3][3] += p4.w*v.w;
            }
        }
    }

    // ---- epilogue: divide by l, store out[b][c][n] ----
#pragma unroll
    for (int nn = 0; nn < 16; ++nn) {
        const float inv = 1.0f / ls[nP0 + nn];
        const int ng = q0 + nP0 + nn;
#pragma unroll
        for (int cc = 0; cc < 4; ++cc) {
            out[((size_t)b * CIN + (c0 + cc)) * NN + ng] = O[nn][cc] * inv;
        }
    }
}

extern "C" void kernel_launch(void* const* d_in, const int* in_sizes, int n_in,
                              void* d_out, int out_size, void* d_ws, size_t ws_size,
                              hipStream_t stream) {
    const float* p  = (const float*)d_in[0];
    const float* bv = (const float*)d_in[1];
    const float* Wq = (const float*)d_in[2];
    const float* bq = (const float*)d_in[3];
    const float* Wk = (const float*)d_in[4];
    const float* bk = (const float*)d_in[5];
    float* outp = (float*)d_out;

    float* Qws  = (float*)d_ws;                                 // 8*4096*128 f32 = 16.8 MB
    float* Ktws = Qws  + (size_t)B_ * NN * COUT;                // 16.8 MB
    float* Vtws = Ktws + (size_t)B_ * NN * COUT;                // 8*4096*256 f32 = 33.6 MB

    proj_kernel<<<512, 256, 0, stream>>>(p,  Wq, bq, Qws);
    proj_kernel<<<512, 256, 0, stream>>>(bv, Wk, bk, Ktws);
    transpose_kernel<<<2048, 256, 0, stream>>>(bv, Vtws);
    flash_kernel<<<512, 256, 0, stream>>>(Qws, Ktws, Vtws, outp);
}

// Round 2
// 681.067 us; speedup vs baseline: 3.1194x; 3.1194x over previous
//
#include <hip/hip_runtime.h>
#include <math.h>

// SpatialAttention B=8, C_IN=256 (d_v), C_OUT=128 (d_qk), N=4096.
// Round 2: MFMA flash attention.
//   proj (fp32 VALU) -> Q,Kt fp16 [b][n][128]
//   cvt: b fp32 -> V bf16 [b][c][m] (native layout == PV B-frag layout)
//   flash: S via mfma f16, P=exp(S) unnormalized in bf16 (no max needed:
//          |S|<~25 -> exp fits fp32/bf16 range), PV via mfma bf16,
//          l summed in fp32 regs, divide in epilogue.

#define B_   8
#define CIN  256
#define COUT 128
#define NN   4096

typedef _Float16 half8 __attribute__((ext_vector_type(8)));
typedef short    short8 __attribute__((ext_vector_type(8)));
typedef float    f32x4 __attribute__((ext_vector_type(4)));

__device__ __forceinline__ unsigned short f2bf(float f) {
    union { float f; unsigned u; } v; v.f = f;
    return (unsigned short)((v.u + 0x7FFFu + ((v.u >> 16) & 1u)) >> 16);
}

// out[b][n][o] = (fp16) sum_c in[b][c][n] * W[o][c] + bias[o]
__global__ __launch_bounds__(256) void proj_kernel(const float* __restrict__ in,
                                                   const float* __restrict__ W,
                                                   const float* __restrict__ bias,
                                                   _Float16* __restrict__ out) {
    const int bx = blockIdx.x;           // 512 blocks: b*64 + ntile
    const int b  = bx >> 6;
    const int n0 = (bx & 63) << 6;
    const int t  = threadIdx.x;
    const int o  = t & 127;
    const int half_ = t >> 7;
    const int nbase = n0 + half_ * 32;

    float acc[32];
    const float bo = bias[o];
#pragma unroll
    for (int i = 0; i < 32; ++i) acc[i] = bo;

    const float* wrow = W + o * CIN;
    const float* inb  = in + (size_t)b * CIN * NN + nbase;
    for (int c = 0; c < CIN; c += 4) {
        const float4 w4 = *(const float4*)(wrow + c);
        const float wv[4] = {w4.x, w4.y, w4.z, w4.w};
#pragma unroll
        for (int cc = 0; cc < 4; ++cc) {
            const float* src = inb + (size_t)(c + cc) * NN;
            const float wvc = wv[cc];
#pragma unroll
            for (int k = 0; k < 8; ++k) {
                float4 v = *(const float4*)(src + k * 4);
                acc[k*4+0] += wvc * v.x;
                acc[k*4+1] += wvc * v.y;
                acc[k*4+2] += wvc * v.z;
                acc[k*4+3] += wvc * v.w;
            }
        }
    }
    _Float16* outp = out + ((size_t)b * NN + nbase) * COUT + o;
#pragma unroll
    for (int i = 0; i < 32; ++i) outp[(size_t)i * COUT] = (_Float16)acc[i];
}

// fp32 -> bf16 bitwise convert, same layout. 8192 blocks x 256 thr, 1 float4 each.
__global__ __launch_bounds__(256) void cvt_kernel(const float* __restrict__ in,
                                                  unsigned short* __restrict__ out) {
    const int idx = blockIdx.x * 256 + threadIdx.x;
    float4 v = ((const float4*)in)[idx];
    unsigned long long pk = (unsigned long long)f2bf(v.x)
                          | ((unsigned long long)f2bf(v.y) << 16)
                          | ((unsigned long long)f2bf(v.z) << 32)
                          | ((unsigned long long)f2bf(v.w) << 48);
    ((unsigned long long*)out)[idx] = pk;
}

// Q,Kt fp16 [b][4096][128]; V bf16 [b][256][4096]; out fp32 [b][256][4096]
__global__ __launch_bounds__(256) void flash_kernel(const _Float16* __restrict__ Q,
                                                    const _Float16* __restrict__ Kt,
                                                    const unsigned short* __restrict__ V,
                                                    float* __restrict__ out) {
    // LDS. Row pitches padded for conflict-free b128 frag reads.
    __shared__ __align__(16) _Float16      Ksh[32 * 136];       // 8704 B (pitch 272B -> 2-way)
    __shared__ __align__(16) unsigned short Vsh[256 * 40];      // 20480 B (pitch 80B -> 2-way)
    __shared__ __align__(16) unsigned short Psh[4 * 16 * 40];   // 5120 B, per-wave regions

    const int bx   = blockIdx.x;          // 512 = B * 64 q-tiles
    const int b    = bx >> 6;
    const int q0   = (bx & 63) << 6;
    const int t    = threadIdx.x;
    const int w    = t >> 6;
    const int lane = t & 63;
    const int l15  = lane & 15;
    const int quad = lane >> 4;
    const int q8   = quad * 8;

    const _Float16* Qg = Q  + (size_t)b * NN * COUT;
    const _Float16* Kg = Kt + (size_t)b * NN * COUT;
    const unsigned short* Vg = V + (size_t)b * CIN * NN;

    // ---- Q fragments for this wave's 16 rows, kept in registers all kernel ----
    half8 Qf[4];
    {
        const _Float16* qr = Qg + (size_t)(q0 + w * 16 + l15) * COUT;
#pragma unroll
        for (int s = 0; s < 4; ++s)
            Qf[s] = *(const half8*)(qr + s * 32 + q8);
    }

    // staging maps (hoisted)
    const int krow = t >> 4, kch = t & 15;        // K tile: 32 rows x 16 chunks(16B)
    const int vrow = t >> 2, vch = t & 3;         // V tile: 256 rows x 4 chunks(16B)

    f32x4 O[16];
#pragma unroll
    for (int i = 0; i < 16; ++i) O[i] = (f32x4){0.f, 0.f, 0.f, 0.f};
    float lsum[4] = {0.f, 0.f, 0.f, 0.f};

    unsigned short* pw = Psh + w * 640;           // this wave's P region [16][40]

    for (int k0 = 0; k0 < NN; k0 += 32) {
        __syncthreads();                           // prev tile's readers done
        // ---- stage K tile (8 KB, contiguous in global) ----
        {
            int4 a0 = *(const int4*)(Kg + (size_t)(k0 + krow) * COUT + kch * 8);
            int4 a1 = *(const int4*)(Kg + (size_t)(k0 + krow + 16) * COUT + kch * 8);
            *(int4*)(Ksh + krow * 136 + kch * 8) = a0;
            *(int4*)(Ksh + (krow + 16) * 136 + kch * 8) = a1;
        }
        // ---- stage V tile (16 KB, 64B per c-row) ----
#pragma unroll
        for (int i = 0; i < 4; ++i) {
            int c = vrow + i * 64;
            int4 vv = *(const int4*)(Vg + (size_t)c * NN + k0 + vch * 8);
            *(int4*)(Vsh + c * 40 + vch * 8) = vv;
        }
        __syncthreads();

        // ---- S = Q K^T : two 16x16 m-groups, K=128 in 4 steps ----
        f32x4 S0 = {0.f, 0.f, 0.f, 0.f}, S1 = {0.f, 0.f, 0.f, 0.f};
        {
            const _Float16* kr = Ksh + l15 * 136;
#pragma unroll
            for (int s = 0; s < 4; ++s) {
                half8 kf0 = *(const half8*)(kr + s * 32 + q8);
                half8 kf1 = *(const half8*)(kr + 16 * 136 + s * 32 + q8);
                S0 = __builtin_amdgcn_mfma_f32_16x16x32_f16(Qf[s], kf0, S0, 0, 0, 0);
                S1 = __builtin_amdgcn_mfma_f32_16x16x32_f16(Qf[s], kf1, S1, 0, 0, 0);
            }
        }

        // ---- P = exp(S) unnormalized; accumulate l; write bf16 P to wave-LDS ----
        // C layout: row n_loc = quad*4+reg, col m_loc = (g)*16 + l15
        {
            unsigned short* pcol = pw + l15;
#pragma unroll
            for (int r = 0; r < 4; ++r) {
                float e0 = __expf(S0[r]);
                float e1 = __expf(S1[r]);
                lsum[r] += e0 + e1;
                pcol[(quad * 4 + r) * 40]      = f2bf(e0);
                pcol[(quad * 4 + r) * 40 + 16] = f2bf(e1);
            }
        }

        // ---- PV: O[n][c] += P[n][m] V[m][c]  (wave-private P, no barrier) ----
        {
            short8 pf = *(const short8*)(pw + l15 * 40 + q8);   // A-frag [n=l15][m=q8..]
            const unsigned short* vb0 = Vsh + l15 * 40 + q8;
#pragma unroll
            for (int cg = 0; cg < 16; ++cg) {
                short8 vf = *(const short8*)(vb0 + cg * 16 * 40);
                O[cg] = __builtin_amdgcn_mfma_f32_16x16x32_bf16(pf, vf, O[cg], 0, 0, 0);
            }
        }
    }

    // ---- epilogue: finish row sums (over the 16 cols held per lane-group) ----
    float inv[4];
#pragma unroll
    for (int r = 0; r < 4; ++r) {
        float s = lsum[r];
        s += __shfl_xor(s, 1);
        s += __shfl_xor(s, 2);
        s += __shfl_xor(s, 4);
        s += __shfl_xor(s, 8);
        inv[r] = 1.0f / s;
    }
    float* ob = out + (size_t)b * CIN * NN + q0 + w * 16 + quad * 4;
#pragma unroll
    for (int cg = 0; cg < 16; ++cg) {
        const int c = cg * 16 + l15;
#pragma unroll
        for (int r = 0; r < 4; ++r)
            ob[(size_t)c * NN + r] = O[cg][r] * inv[r];
    }
}

extern "C" void kernel_launch(void* const* d_in, const int* in_sizes, int n_in,
                              void* d_out, int out_size, void* d_ws, size_t ws_size,
                              hipStream_t stream) {
    const float* p  = (const float*)d_in[0];
    const float* bv = (const float*)d_in[1];
    const float* Wq = (const float*)d_in[2];
    const float* bq = (const float*)d_in[3];
    const float* Wk = (const float*)d_in[4];
    const float* bk = (const float*)d_in[5];
    float* outp = (float*)d_out;

    char* ws = (char*)d_ws;
    _Float16* Qh       = (_Float16*)ws;                              // 4.2 MB
    _Float16* Kth      = (_Float16*)(ws + (size_t)B_ * NN * COUT * 2);   // 4.2 MB
    unsigned short* Vb = (unsigned short*)(ws + (size_t)2 * B_ * NN * COUT * 2); // 16.8 MB

    proj_kernel<<<512, 256, 0, stream>>>(p,  Wq, bq, Qh);
    proj_kernel<<<512, 256, 0, stream>>>(bv, Wk, bk, Kth);
    cvt_kernel<<<(B_ * CIN * NN) / 1024, 256, 0, stream>>>(bv, Vb);
    flash_kernel<<<512, 256, 0, stream>>>(Qh, Kth, Vb, outp);
}

// Round 3
// 364.133 us; speedup vs baseline: 5.8344x; 1.8704x over previous
//
#include <hip/hip_runtime.h>
#include <math.h>

// SpatialAttention B=8, C_IN=256 (d_v), C_OUT=128 (d_qk), N=4096.
// Round 3: projections moved to MFMA.
//   cvt_w : Wq,Wk fp32 -> fp16
//   cvt_pb: p,b fp32 [b][c][n] -> pT,bT fp16 [b][n][c] (LDS transpose);
//           b also -> Vb bf16 [b][c][n] (straight) in the same read pass
//   proj2 : Q = pT*Wq^T + bq (MFMA f16, fp32 accum), fp16 out [b][n][o]
//   flash : unchanged round-2 kernel (S mfma f16, P=exp(S) bf16 unnormalized,
//           PV mfma bf16, divide-by-l epilogue)

#define B_   8
#define CIN  256
#define COUT 128
#define NN   4096

typedef _Float16 half8 __attribute__((ext_vector_type(8)));
typedef short    short8 __attribute__((ext_vector_type(8)));
typedef float    f32x4 __attribute__((ext_vector_type(4)));

__device__ __forceinline__ unsigned short f2bf(float f) {
    union { float f; unsigned u; } v; v.f = f;
    return (unsigned short)((v.u + 0x7FFFu + ((v.u >> 16) & 1u)) >> 16);
}
__device__ __forceinline__ unsigned short f2h(float f) {
    union { _Float16 h; unsigned short u; } v; v.h = (_Float16)f;
    return v.u;
}

// ---- Wq/Wk fp32 -> fp16 (each 128x256) ----
__global__ __launch_bounds__(256) void cvt_w(const float* __restrict__ Wq,
                                             const float* __restrict__ Wk,
                                             _Float16* __restrict__ Whq,
                                             _Float16* __restrict__ Whk) {
    const int bx = blockIdx.x, t = threadIdx.x;
    const float* src = (bx < 32) ? Wq : Wk;
    _Float16* dst = (bx < 32) ? Whq : Whk;
    const int idx = (bx & 31) * 256 + t;          // float4 index
    float4 v = ((const float4*)src)[idx];
    unsigned long long pk = (unsigned long long)f2h(v.x)
                          | ((unsigned long long)f2h(v.y) << 16)
                          | ((unsigned long long)f2h(v.z) << 32)
                          | ((unsigned long long)f2h(v.w) << 48);
    ((unsigned long long*)dst)[idx] = pk;
}

// ---- p,b [b][c][n] fp32 -> pT,bT [b][n][c] fp16; b also -> Vb bf16 [b][c][n] ----
__global__ __launch_bounds__(256) void cvt_pb(const float* __restrict__ p,
                                              const float* __restrict__ bsrc,
                                              _Float16* __restrict__ pT,
                                              _Float16* __restrict__ bT,
                                              unsigned short* __restrict__ Vb) {
    __shared__ unsigned short T[64 * 66];         // pitch 66: scalar writes 4-way, b32 reads 2-way
    const int bx  = blockIdx.x;                   // 4096 = 2 src * 8 b * 4 ctiles * 64 ntiles
    const int isB = bx >> 11;
    const int bx2 = bx & 2047;
    const int bi  = bx2 >> 8;
    const int c0  = ((bx2 >> 6) & 3) << 6;
    const int n0  = (bx2 & 63) << 6;
    const int t   = threadIdx.x;
    const int r   = t >> 2;                       // c-local row
    const int j0  = (t & 3) << 4;                 // n-local chunk
    const float* src = (isB ? bsrc : p) + ((size_t)(bi * CIN + c0 + r) * NN + n0 + j0);
    float v[16];
#pragma unroll
    for (int k = 0; k < 4; ++k) {
        float4 f = *(const float4*)(src + k * 4);
        v[k*4] = f.x; v[k*4+1] = f.y; v[k*4+2] = f.z; v[k*4+3] = f.w;
    }
#pragma unroll
    for (int j = 0; j < 16; ++j) T[(j0 + j) * 66 + r] = f2h(v[j]);
    if (isB) {
        unsigned short o[16];
#pragma unroll
        for (int j = 0; j < 16; ++j) o[j] = f2bf(v[j]);
        unsigned short* dst = Vb + (size_t)(bi * CIN + c0 + r) * NN + n0 + j0;
        *(int4*)dst = *(int4*)o;
        *(int4*)(dst + 8) = *(int4*)(o + 8);
    }
    __syncthreads();
    const int i = t >> 2, ch = t & 3;             // n-local row, c-chunk
    unsigned short o2[16];
#pragma unroll
    for (int k = 0; k < 8; ++k)
        *(unsigned int*)&o2[2 * k] = *(const unsigned int*)&T[i * 66 + ch * 16 + 2 * k];
    _Float16* dstT = (isB ? bT : pT) + ((size_t)(bi * NN + n0 + i) * CIN + c0 + ch * 16);
    *(int4*)dstT = *(int4*)o2;
    *(int4*)(dstT + 8) = *(int4*)(o2 + 8);
}

// ---- MFMA projection: out[b][n][o] = fp16( sum_c X[b][n][c]*Wh[o][c] + bias[o] ) ----
__global__ __launch_bounds__(256) void proj2(const _Float16* __restrict__ X,   // [B][NN][CIN]
                                             const _Float16* __restrict__ Wh,  // [COUT][CIN]
                                             const float* __restrict__ bias,
                                             _Float16* __restrict__ out) {     // [B][NN][COUT]
    __shared__ __align__(16) unsigned short Ash[64 * 264];   // 64 rows x 256c + 8 pad
    const int bx = blockIdx.x, b = bx >> 6, n0 = (bx & 63) << 6;
    const int t = threadIdx.x;
    {   // stage 64x256 fp16 tile, coalesced
        const int r = t >> 2, cb = (t & 3) * 64;
        const _Float16* g = X + ((size_t)(b * NN + n0 + r) * CIN + cb);
#pragma unroll
        for (int k = 0; k < 8; ++k)
            *(int4*)&Ash[r * 264 + cb + k * 8] = *(const int4*)(g + k * 8);
    }
    __syncthreads();
    const int w = t >> 6, lane = t & 63, l15 = lane & 15, quad = lane >> 4, q8 = quad * 8;
    half8 a[8];
#pragma unroll
    for (int s = 0; s < 8; ++s)
        a[s] = *(const half8*)&Ash[(w * 16 + l15) * 264 + s * 32 + q8];
    f32x4 D[8];
#pragma unroll
    for (int og = 0; og < 8; ++og) D[og] = (f32x4){0.f, 0.f, 0.f, 0.f};
#pragma unroll
    for (int s = 0; s < 8; ++s) {
        const _Float16* wp = Wh + (size_t)l15 * CIN + s * 32 + q8;
#pragma unroll
        for (int og = 0; og < 8; ++og) {
            half8 wf = *(const half8*)(wp + og * 16 * CIN);   // L2-hot
            D[og] = __builtin_amdgcn_mfma_f32_16x16x32_f16(a[s], wf, D[og], 0, 0, 0);
        }
    }
    const int nrow = n0 + w * 16 + quad * 4;
#pragma unroll
    for (int og = 0; og < 8; ++og) {
        const int o = og * 16 + l15;
        const float bo = bias[o];
        _Float16* op = out + ((size_t)(b * NN + nrow) * COUT + o);
#pragma unroll
        for (int r2 = 0; r2 < 4; ++r2)
            op[(size_t)r2 * COUT] = (_Float16)(D[og][r2] + bo);
    }
}

// ---- flash attention (unchanged from round 2) ----
__global__ __launch_bounds__(256) void flash_kernel(const _Float16* __restrict__ Q,
                                                    const _Float16* __restrict__ Kt,
                                                    const unsigned short* __restrict__ V,
                                                    float* __restrict__ out) {
    __shared__ __align__(16) _Float16       Ksh[32 * 136];
    __shared__ __align__(16) unsigned short Vsh[256 * 40];
    __shared__ __align__(16) unsigned short Psh[4 * 16 * 40];

    const int bx   = blockIdx.x;
    const int b    = bx >> 6;
    const int q0   = (bx & 63) << 6;
    const int t    = threadIdx.x;
    const int w    = t >> 6;
    const int lane = t & 63;
    const int l15  = lane & 15;
    const int quad = lane >> 4;
    const int q8   = quad * 8;

    const _Float16* Qg = Q  + (size_t)b * NN * COUT;
    const _Float16* Kg = Kt + (size_t)b * NN * COUT;
    const unsigned short* Vg = V + (size_t)b * CIN * NN;

    half8 Qf[4];
    {
        const _Float16* qr = Qg + (size_t)(q0 + w * 16 + l15) * COUT;
#pragma unroll
        for (int s = 0; s < 4; ++s)
            Qf[s] = *(const half8*)(qr + s * 32 + q8);
    }

    const int krow = t >> 4, kch = t & 15;
    const int vrow = t >> 2, vch = t & 3;

    f32x4 O[16];
#pragma unroll
    for (int i = 0; i < 16; ++i) O[i] = (f32x4){0.f, 0.f, 0.f, 0.f};
    float lsum[4] = {0.f, 0.f, 0.f, 0.f};

    unsigned short* pw = Psh + w * 640;

    for (int k0 = 0; k0 < NN; k0 += 32) {
        __syncthreads();
        {
            int4 a0 = *(const int4*)(Kg + (size_t)(k0 + krow) * COUT + kch * 8);
            int4 a1 = *(const int4*)(Kg + (size_t)(k0 + krow + 16) * COUT + kch * 8);
            *(int4*)(Ksh + krow * 136 + kch * 8) = a0;
            *(int4*)(Ksh + (krow + 16) * 136 + kch * 8) = a1;
        }
#pragma unroll
        for (int i = 0; i < 4; ++i) {
            int c = vrow + i * 64;
            int4 vv = *(const int4*)(Vg + (size_t)c * NN + k0 + vch * 8);
            *(int4*)(Vsh + c * 40 + vch * 8) = vv;
        }
        __syncthreads();

        f32x4 S0 = {0.f, 0.f, 0.f, 0.f}, S1 = {0.f, 0.f, 0.f, 0.f};
        {
            const _Float16* kr = Ksh + l15 * 136;
#pragma unroll
            for (int s = 0; s < 4; ++s) {
                half8 kf0 = *(const half8*)(kr + s * 32 + q8);
                half8 kf1 = *(const half8*)(kr + 16 * 136 + s * 32 + q8);
                S0 = __builtin_amdgcn_mfma_f32_16x16x32_f16(Qf[s], kf0, S0, 0, 0, 0);
                S1 = __builtin_amdgcn_mfma_f32_16x16x32_f16(Qf[s], kf1, S1, 0, 0, 0);
            }
        }
        {
            unsigned short* pcol = pw + l15;
#pragma unroll
            for (int r = 0; r < 4; ++r) {
                float e0 = __expf(S0[r]);
                float e1 = __expf(S1[r]);
                lsum[r] += e0 + e1;
                pcol[(quad * 4 + r) * 40]      = f2bf(e0);
                pcol[(quad * 4 + r) * 40 + 16] = f2bf(e1);
            }
        }
        {
            short8 pf = *(const short8*)(pw + l15 * 40 + q8);
            const unsigned short* vb0 = Vsh + l15 * 40 + q8;
#pragma unroll
            for (int cg = 0; cg < 16; ++cg) {
                short8 vf = *(const short8*)(vb0 + cg * 16 * 40);
                O[cg] = __builtin_amdgcn_mfma_f32_16x16x32_bf16(pf, vf, O[cg], 0, 0, 0);
            }
        }
    }

    float inv[4];
#pragma unroll
    for (int r = 0; r < 4; ++r) {
        float s = lsum[r];
        s += __shfl_xor(s, 1);
        s += __shfl_xor(s, 2);
        s += __shfl_xor(s, 4);
        s += __shfl_xor(s, 8);
        inv[r] = 1.0f / s;
    }
    float* ob = out + (size_t)b * CIN * NN + q0 + w * 16 + quad * 4;
#pragma unroll
    for (int cg = 0; cg < 16; ++cg) {
        const int c = cg * 16 + l15;
#pragma unroll
        for (int r = 0; r < 4; ++r)
            ob[(size_t)c * NN + r] = O[cg][r] * inv[r];
    }
}

extern "C" void kernel_launch(void* const* d_in, const int* in_sizes, int n_in,
                              void* d_out, int out_size, void* d_ws, size_t ws_size,
                              hipStream_t stream) {
    const float* p  = (const float*)d_in[0];
    const float* bv = (const float*)d_in[1];
    const float* Wq = (const float*)d_in[2];
    const float* bq = (const float*)d_in[3];
    const float* Wk = (const float*)d_in[4];
    const float* bk = (const float*)d_in[5];
    float* outp = (float*)d_out;

    char* ws = (char*)d_ws;
    const size_t szT = (size_t)B_ * NN * CIN * 2;    // 16.8 MB
    const size_t szQ = (size_t)B_ * NN * COUT * 2;   // 8.4 MB
    _Float16*       pT  = (_Float16*)ws;
    _Float16*       bT  = (_Float16*)(ws + szT);
    unsigned short* Vb  = (unsigned short*)(ws + 2 * szT);
    _Float16*       Qh  = (_Float16*)(ws + 3 * szT);
    _Float16*       Kth = (_Float16*)(ws + 3 * szT + szQ);
    _Float16*       Whq = (_Float16*)(ws + 3 * szT + 2 * szQ);
    _Float16*       Whk = (_Float16*)(ws + 3 * szT + 2 * szQ + (size_t)COUT * CIN * 2);

    cvt_w<<<64, 256, 0, stream>>>(Wq, Wk, Whq, Whk);
    cvt_pb<<<4096, 256, 0, stream>>>(p, bv, pT, bT, Vb);
    proj2<<<512, 256, 0, stream>>>(pT, Whq, bq, Qh);
    proj2<<<512, 256, 0, stream>>>(bT, Whk, bk, Kth);
    flash_kernel<<<512, 256, 0, stream>>>(Qh, Kth, Vb, outp);
}